// Round 17
// baseline (146.421 us; speedup 1.0000x reference)
//
#include <hip/hip_runtime.h>
#include <math.h>

#define NN 20000
#define NE 640000
#define HD 128
#define ROWS 32                // encoder tile
#define NBLK (NN / ROWS)       // 625 (encoder grid)
#define LROWS 16               // layer tile
#define LNBLK (NN / LROWS)     // 1250 (layer grid)
#define CAP 96                 // max degree capacity (Poisson(32) max ~60)
#define NPART 8
#define PART_SZ (NN / NPART)   // 2500

typedef __attribute__((ext_vector_type(8))) short bf16x8;
typedef __attribute__((ext_vector_type(4))) float f32x4;

__device__ __forceinline__ unsigned short f2bf(float f) {
    unsigned u = __float_as_uint(f);
    unsigned r = u + 0x7FFFu + ((u >> 16) & 1u);   // RNE
    return (unsigned short)(r >> 16);
}
__device__ __forceinline__ float bf2f(unsigned short b) {
    return __uint_as_float(((unsigned)b) << 16);
}

// edge record: src (15 bits) << 17 | ea as 17-bit fixed point [0,1)
__device__ __forceinline__ unsigned pack_edge(int src, float ea) {
    return ((unsigned)src << 17) | (unsigned)(ea * 131072.0f);
}

// ---------------- weight repack + cnt zero (fused) ----------------
__global__ __launch_bounds__(256) void k_pack_fill(const float* __restrict__ msg_w,
                                                   const float* __restrict__ upd_w,
                                                   unsigned short* __restrict__ wp,
                                                   int* __restrict__ cnt) {
    int tid = blockIdx.x * 256 + threadIdx.x;
    if (tid < 8192) {
        int m = tid >> 11;
        int rem = tid & 2047;
        int ct = rem >> 8;
        int ks = (rem >> 6) & 3;
        int lane = rem & 63;
        const float* W = (m == 0) ? msg_w
                       : (m == 1) ? msg_w + HD * HD
                       : (m == 2) ? upd_w
                                  : upd_w + HD * HD;
        int k0 = ks * 32 + (lane >> 4) * 8;
        int col = ct * 16 + (lane & 15);
        unsigned short* outp = wp + (size_t)m * 16384 + ((ct * 4 + ks) * 64 + lane) * 8;
#pragma unroll
        for (int j = 0; j < 8; j++) outp[j] = f2bf(W[(k0 + j) * HD + col]);
    }
    int z = tid - 8192;
    if (z >= 0 && z < NN) cnt[z] = 0;
}

// ---------------- XCD-partitioned bucket scatter ----------------
__global__ __launch_bounds__(256) void k_scatter(const int* __restrict__ src,
                                                 const int4* __restrict__ dst4,
                                                 const float* __restrict__ ea,
                                                 int* __restrict__ cnt,
                                                 unsigned* __restrict__ edges) {
    int part = blockIdx.x & (NPART - 1);
    int blk = blockIdx.x >> 3;
    int nblk = gridDim.x >> 3;
    int lo = part * PART_SZ;
    for (int e4 = blk * 256 + threadIdx.x; e4 < NE / 4; e4 += nblk * 256) {
        int4 d = dst4[e4];
        int e = e4 * 4;
        if ((unsigned)(d.x - lo) < (unsigned)PART_SZ) {
            int p = atomicAdd(&cnt[d.x], 1);
            if (p < CAP) edges[(size_t)d.x * CAP + p] = pack_edge(src[e], ea[e]);
        }
        if ((unsigned)(d.y - lo) < (unsigned)PART_SZ) {
            int p = atomicAdd(&cnt[d.y], 1);
            if (p < CAP) edges[(size_t)d.y * CAP + p] = pack_edge(src[e + 1], ea[e + 1]);
        }
        if ((unsigned)(d.z - lo) < (unsigned)PART_SZ) {
            int p = atomicAdd(&cnt[d.z], 1);
            if (p < CAP) edges[(size_t)d.z * CAP + p] = pack_edge(src[e + 2], ea[e + 2]);
        }
        if ((unsigned)(d.w - lo) < (unsigned)PART_SZ) {
            int p = atomicAdd(&cnt[d.w], 1);
            if (p < CAP) edges[(size_t)d.w * CAP + p] = pack_edge(src[e + 3], ea[e + 3]);
        }
    }
}

// ---------------- MFMA helpers ----------------
__device__ __forceinline__ bf16x8 ldfragA(const unsigned short S[][HD], int row, int ks, int q) {
    int k0 = (ks * 32 + q * 8) ^ ((row & 7) << 3);
    return *(const bf16x8*)&S[row][k0];
}

// ---------------- encoder + mm1 (MFMA, 128 threads, 32 rows) + bucket padding ----------------
__global__ __launch_bounds__(128) void k_enc_mm1(const float* __restrict__ x,
                                                 const float* __restrict__ enc_w,
                                                 const float* __restrict__ enc_b,
                                                 const unsigned short* __restrict__ wp,
                                                 const float* __restrict__ msg_b,
                                                 unsigned short* __restrict__ h_bf,
                                                 unsigned short* __restrict__ Abf,
                                                 unsigned short* __restrict__ Bbf,
                                                 const int* __restrict__ cnt,
                                                 unsigned* __restrict__ edges) {
    __shared__ unsigned short hsN[ROWS][HD];
    int t = threadIdx.x;
    int n0 = blockIdx.x * ROWS;
    // pad each node's bucket to a multiple of 16 by replicating edge 0
    if (t < ROWS) {
        int i = n0 + t;
        int ci = cnt[i];
        if (ci > CAP) ci = CAP;
        if (ci > 0) {
            int ce = (ci + 15) & ~15;
            if (ce > CAP) ce = CAP;
            unsigned e0 = edges[(size_t)i * CAP];
            for (int j = ci; j < ce; j++) edges[(size_t)i * CAP + j] = e0;
        }
    }
    {
        float ew = enc_w[t], eb = enc_b[t];
#pragma unroll
        for (int r = 0; r < ROWS; r++) {
            unsigned short bv = f2bf(fmaf(x[n0 + r], ew, eb));
            hsN[r][t ^ ((r & 7) << 3)] = bv;
            h_bf[(size_t)(n0 + r) * HD + t] = bv;
        }
    }
    __syncthreads();
    int lane = t & 63, wv = t >> 6;
    int rbase = wv * 16;
    int cl = lane & 15, q = lane >> 4;
    const unsigned short* wd = wp;
    const unsigned short* wsr = wp + 16384;
    f32x4 aacc[8], bacc[8];
#pragma unroll
    for (int ct = 0; ct < 8; ct++) {
        float bv = msg_b[ct * 16 + cl];
        aacc[ct] = (f32x4){bv, bv, bv, bv};
        bacc[ct] = (f32x4){0.f, 0.f, 0.f, 0.f};
    }
#pragma unroll
    for (int ks = 0; ks < 4; ks++) {
        bf16x8 hF = ldfragA(hsN, rbase + cl, ks, q);
#pragma unroll
        for (int ct = 0; ct < 8; ct++) {
            bf16x8 w1 = *(const bf16x8*)&wd[((ct * 4 + ks) * 64 + lane) * 8];
            bf16x8 w2 = *(const bf16x8*)&wsr[((ct * 4 + ks) * 64 + lane) * 8];
            aacc[ct] = __builtin_amdgcn_mfma_f32_16x16x32_bf16(hF, w1, aacc[ct], 0, 0, 0);
            bacc[ct] = __builtin_amdgcn_mfma_f32_16x16x32_bf16(hF, w2, bacc[ct], 0, 0, 0);
        }
    }
#pragma unroll
    for (int ct = 0; ct < 8; ct++) {
        int col = ct * 16 + cl;
#pragma unroll
        for (int reg = 0; reg < 4; reg++) {
            int row = n0 + rbase + q * 4 + reg;
            Abf[(size_t)row * HD + col] = f2bf(aacc[ct][reg]);
            Bbf[(size_t)row * HD + col] = f2bf(bacc[ct][reg]);
        }
    }
}

// ---------------- fused layer: aggr + mm2 + [mm1 | decoder] ----------------
// 1024 threads = 16 waves, 16 nodes/block: ONE node per wave (min serial
// gather chain). Waves 0-7 do the MFMA phases (8 col-tiles); 8-15 idle there.
template <int FINAL>
__global__ __launch_bounds__(1024) void k_layer(unsigned short* __restrict__ h_bf,
                                                const unsigned short* __restrict__ Ain,
                                                const unsigned short* __restrict__ Bin,
                                                const int* __restrict__ cnt,
                                                const unsigned* __restrict__ edges,
                                                const float* __restrict__ msg_w,
                                                const unsigned short* __restrict__ wp,
                                                const float* __restrict__ upd_b,
                                                const float* __restrict__ msg_b,
                                                unsigned short* __restrict__ Aout,
                                                unsigned short* __restrict__ Bout,
                                                const float* __restrict__ dec_w,
                                                const float* __restrict__ dec_b,
                                                const float* __restrict__ term_w,
                                                float* __restrict__ out,
                                                float* __restrict__ partials) {
    __shared__ unsigned short hsA[LROWS][HD];
    __shared__ unsigned short hsG[LROWS][HD];
    __shared__ unsigned short hsN[LROWS][HD];
    __shared__ unsigned erec[LROWS * CAP];   // 6 KB, block's 16 buckets
    __shared__ float tred[16];
    int t = threadIdx.x;
    int wv = t >> 6, lane = t & 63;
    int n0 = blockIdx.x * LROWS;

    // prefetch h rows into registers (t<256 covers 16 rows x 16 chunks)
    bf16x8 hpre;
    if (t < LROWS * 16) {
        int row = t >> 4, ch = t & 15;
        hpre = *(const bf16x8*)&h_bf[(size_t)(n0 + row) * HD + ch * 8];
    }

    // stage the block's edge records into LDS: contiguous region, coalesced
    {
        const unsigned* eg = edges + (size_t)n0 * CAP;
        if (t < 1024) erec[t] = eg[t];
        int idx = t + 1024;
        if (idx < LROWS * CAP) erec[idx] = eg[idx];
    }

    // hoisted per-node metadata (one node per wave; overlaps the staging)
    int i = n0 + wv;
    int ci = cnt[i];
    if (ci > CAP) ci = CAP;
    unsigned av = ((const unsigned*)Ain)[(size_t)i * 64 + lane];
    __syncthreads();   // erec ready

    // ---- phase A: aggregation, 1 node per wave, batch-16 gather (records in LDS) ----
    float2 w = ((const float2*)(msg_w + 256 * HD))[lane];
    const float SC = 1.0f / 131072.0f;
    const unsigned* B32 = (const unsigned*)Bin;
    {
        const unsigned* ep = &erec[wv * CAP];
        float m0 = -INFINITY, m1 = -INFINITY;
        int nb = (ci + 15) >> 4;       // padded: no scalar tail
        for (int bi = 0; bi < nb; bi++) {
            unsigned p[16], b[16];
#pragma unroll
            for (int u = 0; u < 16; u++) p[u] = ep[bi * 16 + u];   // LDS reads
#pragma unroll
            for (int u = 0; u < 16; u++)
                b[u] = B32[(size_t)(p[u] >> 17) * 64 + lane];      // 16 loads in flight
#pragma unroll
            for (int u = 0; u < 16; u++) {
                float ea = (float)(p[u] & 0x1FFFF) * SC;
                m0 = fmaxf(m0, fmaf(ea, w.x, bf2f((unsigned short)b[u])));
                m1 = fmaxf(m1, fmaf(ea, w.y, bf2f((unsigned short)(b[u] >> 16))));
            }
        }
        unsigned short r0 = f2bf(fmaxf(bf2f((unsigned short)av) + m0, 0.f));
        unsigned short r1 = f2bf(fmaxf(bf2f((unsigned short)(av >> 16)) + m1, 0.f));
        int e0 = (2 * lane) ^ ((wv & 7) << 3);
        *(unsigned*)&hsG[wv][e0] = ((unsigned)r1 << 16) | r0;
    }
    // stash prefetched h into swizzled LDS
    if (t < LROWS * 16) {
        int row = t >> 4, ch = t & 15;
        *(bf16x8*)&hsA[row][(ch ^ (row & 7)) * 8] = hpre;
    }
    __syncthreads();

    // ---- phase B: mm2 — waves 0-7, wave wv owns col-tile wv ----
    int q = lane >> 4, cl = lane & 15;
    const unsigned short* wd = wp;
    const unsigned short* wsr = wp + 16384;
    const unsigned short* wu1 = wp + 2 * 16384;
    const unsigned short* wu2 = wp + 3 * 16384;
    if (wv < 8) {
        int ct = wv;
        f32x4 acc;
        {
            float bv = upd_b[ct * 16 + cl];
            acc = (f32x4){bv, bv, bv, bv};
        }
#pragma unroll
        for (int ks = 0; ks < 4; ks++) {
            bf16x8 hF = ldfragA(hsA, cl, ks, q);
            bf16x8 gF = ldfragA(hsG, cl, ks, q);
            bf16x8 w1 = *(const bf16x8*)&wu1[((ct * 4 + ks) * 64 + lane) * 8];
            bf16x8 w2 = *(const bf16x8*)&wu2[((ct * 4 + ks) * 64 + lane) * 8];
            acc = __builtin_amdgcn_mfma_f32_16x16x32_bf16(hF, w1, acc, 0, 0, 0);
            acc = __builtin_amdgcn_mfma_f32_16x16x32_bf16(gF, w2, acc, 0, 0, 0);
        }
        int col = ct * 16 + cl;
#pragma unroll
        for (int reg = 0; reg < 4; reg++) {
            int row = q * 4 + reg;
            hsN[row][col ^ ((row & 7) << 3)] = f2bf(fmaxf(acc[reg], 0.f));
        }
    }
    __syncthreads();

    if (FINAL == 0) {
        // h writeback (all threads, overlaps mm1 below)
        if (t < LROWS * 16) {
            int row = t >> 4, ch = t & 15;
            *(bf16x8*)&h_bf[(size_t)(n0 + row) * HD + ch * 8] =
                *(const bf16x8*)&hsN[row][(ch ^ (row & 7)) * 8];
        }
        // ---- mm1 on h_next: waves 0-7 ----
        if (wv < 8) {
            int ct = wv;
            f32x4 aacc, bacc;
            {
                float bv = msg_b[ct * 16 + cl];
                aacc = (f32x4){bv, bv, bv, bv};
                bacc = (f32x4){0.f, 0.f, 0.f, 0.f};
            }
#pragma unroll
            for (int ks = 0; ks < 4; ks++) {
                bf16x8 hF2 = ldfragA(hsN, cl, ks, q);
                bf16x8 w1 = *(const bf16x8*)&wd[((ct * 4 + ks) * 64 + lane) * 8];
                bf16x8 w2 = *(const bf16x8*)&wsr[((ct * 4 + ks) * 64 + lane) * 8];
                aacc = __builtin_amdgcn_mfma_f32_16x16x32_bf16(hF2, w1, aacc, 0, 0, 0);
                bacc = __builtin_amdgcn_mfma_f32_16x16x32_bf16(hF2, w2, bacc, 0, 0, 0);
            }
            int col = ct * 16 + cl;
#pragma unroll
            for (int reg = 0; reg < 4; reg++) {
                int row = n0 + q * 4 + reg;
                Aout[(size_t)row * HD + col] = f2bf(aacc[reg]);
                Bout[(size_t)row * HD + col] = f2bf(bacc[reg]);
            }
        }
    } else {
        // ---- decoder + termination partial: wave wv reduces row wv ----
        float dw0 = dec_w[lane], dw1 = dec_w[64 + lane];
        float tw0 = term_w[lane], tw1 = term_w[64 + lane];
        int r = wv;
        int sw = (r & 7) << 3;
        float h0 = bf2f(hsN[r][lane ^ sw]);
        float h1 = bf2f(hsN[r][(64 + lane) ^ sw]);
        float s1 = fmaf(h0, dw0, h1 * dw1);
        float s2 = fmaf(h0, tw0, h1 * tw1);
#pragma unroll
        for (int off = 32; off; off >>= 1) {
            s1 += __shfl_xor(s1, off);
            s2 += __shfl_xor(s2, off);
        }
        if (lane == 0) {
            out[n0 + r] = 1.f / (1.f + expf(-(s1 + dec_b[0])));
            tred[wv] = s2;
        }
        __syncthreads();
        if (t == 0) {
            float s = 0.f;
#pragma unroll
            for (int k = 0; k < 16; k++) s += tred[k];
            partials[blockIdx.x] = s;
        }
    }
}

__global__ __launch_bounds__(256) void k_term(const float* __restrict__ partials,
                                              const float* __restrict__ term_b,
                                              float* __restrict__ out) {
    __shared__ float red[256];
    int t = threadIdx.x;
    float s = 0.f;
    for (int i = t; i < LNBLK; i += 256) s += partials[i];
    red[t] = s;
    __syncthreads();
    for (int off = 128; off; off >>= 1) {
        if (t < off) red[t] += red[t + off];
        __syncthreads();
    }
    if (t == 0) {
        float m = red[0] / (float)NN;
        out[NN] = 1.f / (1.f + expf(-(m + term_b[0])));
    }
}

extern "C" void kernel_launch(void* const* d_in, const int* in_sizes, int n_in,
                              void* d_out, int out_size, void* d_ws, size_t ws_size,
                              hipStream_t stream) {
    const float* x        = (const float*)d_in[0];
    const int*   eidx     = (const int*)d_in[1];
    const float* eattr    = (const float*)d_in[2];
    const float* enc_w    = (const float*)d_in[3];
    const float* enc_b    = (const float*)d_in[4];
    const float* msg_w    = (const float*)d_in[5];
    const float* msg_b    = (const float*)d_in[6];
    const float* upd_w    = (const float*)d_in[7];
    const float* upd_b    = (const float*)d_in[8];
    const float* dec_w    = (const float*)d_in[9];
    const float* dec_b    = (const float*)d_in[10];
    const float* term_w   = (const float*)d_in[11];
    const float* term_b   = (const float*)d_in[12];
    float* out = (float*)d_out;

    const int* src = eidx;          // edge_index[0] = source j
    const int* dst = eidx + NE;     // edge_index[1] = target i

    char* ws = (char*)d_ws;
    size_t off = 0;
    auto alloc = [&](size_t bytes) -> void* {
        void* p = ws + off;
        off += (bytes + 255) & ~size_t(255);
        return p;
    };
    unsigned short* h_bf  = (unsigned short*)alloc((size_t)NN * HD * 2);
    unsigned short* A0    = (unsigned short*)alloc((size_t)NN * HD * 2);
    unsigned short* B0    = (unsigned short*)alloc((size_t)NN * HD * 2);
    unsigned short* A1    = (unsigned short*)alloc((size_t)NN * HD * 2);
    unsigned short* B1    = (unsigned short*)alloc((size_t)NN * HD * 2);
    unsigned* edges       = (unsigned*)alloc((size_t)NN * CAP * 4);
    unsigned short* wpack = (unsigned short*)alloc((size_t)4 * 16384 * 2);
    int*   cnt            = (int*)alloc((size_t)NN * 4);
    float* partials       = (float*)alloc((size_t)LNBLK * 4);

    // weight repack + cnt zeroing (one dispatch)
    k_pack_fill<<<(8192 + NN + 255) / 256, 256, 0, stream>>>(msg_w, upd_w, wpack, cnt);
    // XCD-partitioned bucket scatter
    k_scatter<<<NPART * 128, 256, 0, stream>>>(src, (const int4*)dst, eattr, cnt, edges);
    // encoder + first message linear + bucket padding
    k_enc_mm1<<<NBLK, 128, 0, stream>>>(x, enc_w, enc_b, wpack, msg_b, h_bf, A0, B0,
                                        cnt, edges);

    // fused layers (A/B double-buffered)
    k_layer<0><<<LNBLK, 1024, 0, stream>>>(h_bf, A0, B0, cnt, edges, msg_w, wpack,
                                           upd_b, msg_b, A1, B1,
                                           dec_w, dec_b, term_w, out, partials);
    k_layer<0><<<LNBLK, 1024, 0, stream>>>(h_bf, A1, B1, cnt, edges, msg_w, wpack,
                                           upd_b, msg_b, A0, B0,
                                           dec_w, dec_b, term_w, out, partials);
    k_layer<1><<<LNBLK, 1024, 0, stream>>>(h_bf, A0, B0, cnt, edges, msg_w, wpack,
                                           upd_b, msg_b, A1, B1,
                                           dec_w, dec_b, term_w, out, partials);

    k_term<<<1, 256, 0, stream>>>(partials, term_b, out);
}

// Round 18
// 146.097 us; speedup vs baseline: 1.0022x; 1.0022x over previous
//
#include <hip/hip_runtime.h>
#include <math.h>

#define NN 20000
#define NE 640000
#define HD 128
#define ROWS 32                // encoder tile
#define NBLK (NN / ROWS)       // 625 (encoder grid)
#define LROWS 16               // layer tile
#define LNBLK (NN / LROWS)     // 1250 (layer grid)
#define CAP 96                 // max degree capacity (Poisson(32) max ~60)
#define NPART 8
#define PART_SZ (NN / NPART)   // 2500

typedef __attribute__((ext_vector_type(8))) short bf16x8;
typedef __attribute__((ext_vector_type(4))) float f32x4;

__device__ __forceinline__ unsigned short f2bf(float f) {
    unsigned u = __float_as_uint(f);
    unsigned r = u + 0x7FFFu + ((u >> 16) & 1u);   // RNE
    return (unsigned short)(r >> 16);
}
__device__ __forceinline__ float bf2f(unsigned short b) {
    return __uint_as_float(((unsigned)b) << 16);
}

// edge record: src (15 bits) << 17 | ea as 17-bit fixed point [0,1)
__device__ __forceinline__ unsigned pack_edge(int src, float ea) {
    return ((unsigned)src << 17) | (unsigned)(ea * 131072.0f);
}

// ---------------- weight repack + cnt zero (fused) ----------------
__global__ __launch_bounds__(256) void k_pack_fill(const float* __restrict__ msg_w,
                                                   const float* __restrict__ upd_w,
                                                   unsigned short* __restrict__ wp,
                                                   int* __restrict__ cnt) {
    int tid = blockIdx.x * 256 + threadIdx.x;
    if (tid < 8192) {
        int m = tid >> 11;
        int rem = tid & 2047;
        int ct = rem >> 8;
        int ks = (rem >> 6) & 3;
        int lane = rem & 63;
        const float* W = (m == 0) ? msg_w
                       : (m == 1) ? msg_w + HD * HD
                       : (m == 2) ? upd_w
                                  : upd_w + HD * HD;
        int k0 = ks * 32 + (lane >> 4) * 8;
        int col = ct * 16 + (lane & 15);
        unsigned short* outp = wp + (size_t)m * 16384 + ((ct * 4 + ks) * 64 + lane) * 8;
#pragma unroll
        for (int j = 0; j < 8; j++) outp[j] = f2bf(W[(k0 + j) * HD + col]);
    }
    int z = tid - 8192;
    if (z >= 0 && z < NN) cnt[z] = 0;
}

// ---------------- XCD-partitioned bucket scatter ----------------
__global__ __launch_bounds__(256) void k_scatter(const int* __restrict__ src,
                                                 const int4* __restrict__ dst4,
                                                 const float* __restrict__ ea,
                                                 int* __restrict__ cnt,
                                                 unsigned* __restrict__ edges) {
    int part = blockIdx.x & (NPART - 1);
    int blk = blockIdx.x >> 3;
    int nblk = gridDim.x >> 3;
    int lo = part * PART_SZ;
    for (int e4 = blk * 256 + threadIdx.x; e4 < NE / 4; e4 += nblk * 256) {
        int4 d = dst4[e4];
        int e = e4 * 4;
        if ((unsigned)(d.x - lo) < (unsigned)PART_SZ) {
            int p = atomicAdd(&cnt[d.x], 1);
            if (p < CAP) edges[(size_t)d.x * CAP + p] = pack_edge(src[e], ea[e]);
        }
        if ((unsigned)(d.y - lo) < (unsigned)PART_SZ) {
            int p = atomicAdd(&cnt[d.y], 1);
            if (p < CAP) edges[(size_t)d.y * CAP + p] = pack_edge(src[e + 1], ea[e + 1]);
        }
        if ((unsigned)(d.z - lo) < (unsigned)PART_SZ) {
            int p = atomicAdd(&cnt[d.z], 1);
            if (p < CAP) edges[(size_t)d.z * CAP + p] = pack_edge(src[e + 2], ea[e + 2]);
        }
        if ((unsigned)(d.w - lo) < (unsigned)PART_SZ) {
            int p = atomicAdd(&cnt[d.w], 1);
            if (p < CAP) edges[(size_t)d.w * CAP + p] = pack_edge(src[e + 3], ea[e + 3]);
        }
    }
}

// ---------------- MFMA helpers ----------------
__device__ __forceinline__ bf16x8 ldfragA(const unsigned short S[][HD], int row, int ks, int q) {
    int k0 = (ks * 32 + q * 8) ^ ((row & 7) << 3);
    return *(const bf16x8*)&S[row][k0];
}

// ---------------- encoder + mm1 (MFMA, 128 threads, 32 rows) + bucket padding ----------------
__global__ __launch_bounds__(128) void k_enc_mm1(const float* __restrict__ x,
                                                 const float* __restrict__ enc_w,
                                                 const float* __restrict__ enc_b,
                                                 const unsigned short* __restrict__ wp,
                                                 const float* __restrict__ msg_b,
                                                 unsigned short* __restrict__ h_bf,
                                                 unsigned short* __restrict__ Abf,
                                                 unsigned short* __restrict__ Bbf,
                                                 const int* __restrict__ cnt,
                                                 unsigned* __restrict__ edges) {
    __shared__ unsigned short hsN[ROWS][HD];
    int t = threadIdx.x;
    int n0 = blockIdx.x * ROWS;
    // pad each node's bucket to a multiple of 16 by replicating edge 0
    if (t < ROWS) {
        int i = n0 + t;
        int ci = cnt[i];
        if (ci > CAP) ci = CAP;
        if (ci > 0) {
            int ce = (ci + 15) & ~15;
            if (ce > CAP) ce = CAP;
            unsigned e0 = edges[(size_t)i * CAP];
            for (int j = ci; j < ce; j++) edges[(size_t)i * CAP + j] = e0;
        }
    }
    {
        float ew = enc_w[t], eb = enc_b[t];
#pragma unroll
        for (int r = 0; r < ROWS; r++) {
            unsigned short bv = f2bf(fmaf(x[n0 + r], ew, eb));
            hsN[r][t ^ ((r & 7) << 3)] = bv;
            h_bf[(size_t)(n0 + r) * HD + t] = bv;
        }
    }
    __syncthreads();
    int lane = t & 63, wv = t >> 6;
    int rbase = wv * 16;
    int cl = lane & 15, q = lane >> 4;
    const unsigned short* wd = wp;
    const unsigned short* wsr = wp + 16384;
    f32x4 aacc[8], bacc[8];
#pragma unroll
    for (int ct = 0; ct < 8; ct++) {
        float bv = msg_b[ct * 16 + cl];
        aacc[ct] = (f32x4){bv, bv, bv, bv};
        bacc[ct] = (f32x4){0.f, 0.f, 0.f, 0.f};
    }
#pragma unroll
    for (int ks = 0; ks < 4; ks++) {
        bf16x8 hF = ldfragA(hsN, rbase + cl, ks, q);
#pragma unroll
        for (int ct = 0; ct < 8; ct++) {
            bf16x8 w1 = *(const bf16x8*)&wd[((ct * 4 + ks) * 64 + lane) * 8];
            bf16x8 w2 = *(const bf16x8*)&wsr[((ct * 4 + ks) * 64 + lane) * 8];
            aacc[ct] = __builtin_amdgcn_mfma_f32_16x16x32_bf16(hF, w1, aacc[ct], 0, 0, 0);
            bacc[ct] = __builtin_amdgcn_mfma_f32_16x16x32_bf16(hF, w2, bacc[ct], 0, 0, 0);
        }
    }
#pragma unroll
    for (int ct = 0; ct < 8; ct++) {
        int col = ct * 16 + cl;
#pragma unroll
        for (int reg = 0; reg < 4; reg++) {
            int row = n0 + rbase + q * 4 + reg;
            Abf[(size_t)row * HD + col] = f2bf(aacc[ct][reg]);
            Bbf[(size_t)row * HD + col] = f2bf(bacc[ct][reg]);
        }
    }
}

// ---------------- fused layer: aggr + mm2 + [mm1 | decoder] ----------------
// 512 threads = 8 waves, 16 nodes/block. Edge records staged to LDS; the two
// nodes per wave are gathered in ONE interleaved batch loop (32 loads in flight).
template <int FINAL>
__global__ __launch_bounds__(512) void k_layer(unsigned short* __restrict__ h_bf,
                                               const unsigned short* __restrict__ Ain,
                                               const unsigned short* __restrict__ Bin,
                                               const int* __restrict__ cnt,
                                               const unsigned* __restrict__ edges,
                                               const float* __restrict__ msg_w,
                                               const unsigned short* __restrict__ wp,
                                               const float* __restrict__ upd_b,
                                               const float* __restrict__ msg_b,
                                               unsigned short* __restrict__ Aout,
                                               unsigned short* __restrict__ Bout,
                                               const float* __restrict__ dec_w,
                                               const float* __restrict__ dec_b,
                                               const float* __restrict__ term_w,
                                               float* __restrict__ out,
                                               float* __restrict__ partials) {
    __shared__ unsigned short hsA[LROWS][HD];
    __shared__ unsigned short hsG[LROWS][HD];
    __shared__ unsigned short hsN[LROWS][HD];
    __shared__ unsigned erec[LROWS * CAP];   // 6 KB, block's 16 buckets
    __shared__ float tred[8];
    int t = threadIdx.x;
    int wv = t >> 6, lane = t & 63;
    int n0 = blockIdx.x * LROWS;

    // prefetch h rows into registers (t<256 covers 16 rows x 16 chunks)
    bf16x8 hpre;
    if (t < LROWS * 16) {
        int row = t >> 4, ch = t & 15;
        hpre = *(const bf16x8*)&h_bf[(size_t)(n0 + row) * HD + ch * 8];
    }

    // stage the block's edge records into LDS: contiguous region, coalesced
    {
        const unsigned* eg = edges + (size_t)n0 * CAP;
#pragma unroll
        for (int v = 0; v < (LROWS * CAP) / 512; v++)   // 1536/512 = 3
            erec[t + v * 512] = eg[t + v * 512];
    }

    // hoisted per-node metadata (overlaps the staging)
    int i0 = n0 + wv * 2;
    int ci0 = cnt[i0], ci1 = cnt[i0 + 1];
    if (ci0 > CAP) ci0 = CAP;
    if (ci1 > CAP) ci1 = CAP;
    unsigned av0 = ((const unsigned*)Ain)[(size_t)i0 * 64 + lane];
    unsigned av1 = ((const unsigned*)Ain)[(size_t)(i0 + 1) * 64 + lane];
    __syncthreads();   // erec ready

    // ---- phase A: interleaved batch-16 gather for BOTH nodes of this wave ----
    float2 w = ((const float2*)(msg_w + 256 * HD))[lane];
    const float SC = 1.0f / 131072.0f;
    const unsigned* B32 = (const unsigned*)Bin;
    {
        const unsigned* ep0 = &erec[(wv * 2 + 0) * CAP];
        const unsigned* ep1 = &erec[(wv * 2 + 1) * CAP];
        float m00 = -INFINITY, m01 = -INFINITY;   // node 0 cols 2l, 2l+1
        float m10 = -INFINITY, m11 = -INFINITY;   // node 1
        int nb0 = (ci0 + 15) >> 4;   // padded: no scalar tail
        int nb1 = (ci1 + 15) >> 4;
        int nbm = nb0 > nb1 ? nb0 : nb1;
        for (int bi = 0; bi < nbm; bi++) {
            unsigned p0[16], p1[16], b0[16], b1[16];
            bool d0 = bi < nb0, d1 = bi < nb1;     // wave-uniform branches
            if (d0) {
#pragma unroll
                for (int u = 0; u < 16; u++) p0[u] = ep0[bi * 16 + u];
#pragma unroll
                for (int u = 0; u < 16; u++)
                    b0[u] = B32[(size_t)(p0[u] >> 17) * 64 + lane];
            }
            if (d1) {
#pragma unroll
                for (int u = 0; u < 16; u++) p1[u] = ep1[bi * 16 + u];
#pragma unroll
                for (int u = 0; u < 16; u++)
                    b1[u] = B32[(size_t)(p1[u] >> 17) * 64 + lane];
            }
            if (d0) {
#pragma unroll
                for (int u = 0; u < 16; u++) {
                    float ea = (float)(p0[u] & 0x1FFFF) * SC;
                    m00 = fmaxf(m00, fmaf(ea, w.x, bf2f((unsigned short)b0[u])));
                    m01 = fmaxf(m01, fmaf(ea, w.y, bf2f((unsigned short)(b0[u] >> 16))));
                }
            }
            if (d1) {
#pragma unroll
                for (int u = 0; u < 16; u++) {
                    float ea = (float)(p1[u] & 0x1FFFF) * SC;
                    m10 = fmaxf(m10, fmaf(ea, w.x, bf2f((unsigned short)b1[u])));
                    m11 = fmaxf(m11, fmaf(ea, w.y, bf2f((unsigned short)(b1[u] >> 16))));
                }
            }
        }
        int ri0 = wv * 2, ri1 = wv * 2 + 1;
        unsigned short r0 = f2bf(fmaxf(bf2f((unsigned short)av0) + m00, 0.f));
        unsigned short r1 = f2bf(fmaxf(bf2f((unsigned short)(av0 >> 16)) + m01, 0.f));
        *(unsigned*)&hsG[ri0][(2 * lane) ^ ((ri0 & 7) << 3)] = ((unsigned)r1 << 16) | r0;
        unsigned short r2 = f2bf(fmaxf(bf2f((unsigned short)av1) + m10, 0.f));
        unsigned short r3 = f2bf(fmaxf(bf2f((unsigned short)(av1 >> 16)) + m11, 0.f));
        *(unsigned*)&hsG[ri1][(2 * lane) ^ ((ri1 & 7) << 3)] = ((unsigned)r3 << 16) | r2;
    }
    // stash prefetched h into swizzled LDS
    if (t < LROWS * 16) {
        int row = t >> 4, ch = t & 15;
        *(bf16x8*)&hsA[row][(ch ^ (row & 7)) * 8] = hpre;
    }
    __syncthreads();

    // ---- phase B: mm2 — 8 waves, wave wv owns col-tile wv ----
    int q = lane >> 4, cl = lane & 15;
    int ct = wv;
    const unsigned short* wd = wp;
    const unsigned short* wsr = wp + 16384;
    const unsigned short* wu1 = wp + 2 * 16384;
    const unsigned short* wu2 = wp + 3 * 16384;
    f32x4 acc;
    {
        float bv = upd_b[ct * 16 + cl];
        acc = (f32x4){bv, bv, bv, bv};
    }
#pragma unroll
    for (int ks = 0; ks < 4; ks++) {
        bf16x8 hF = ldfragA(hsA, cl, ks, q);
        bf16x8 gF = ldfragA(hsG, cl, ks, q);
        bf16x8 w1 = *(const bf16x8*)&wu1[((ct * 4 + ks) * 64 + lane) * 8];
        bf16x8 w2 = *(const bf16x8*)&wu2[((ct * 4 + ks) * 64 + lane) * 8];
        acc = __builtin_amdgcn_mfma_f32_16x16x32_bf16(hF, w1, acc, 0, 0, 0);
        acc = __builtin_amdgcn_mfma_f32_16x16x32_bf16(gF, w2, acc, 0, 0, 0);
    }
    {
        int col = ct * 16 + cl;
#pragma unroll
        for (int reg = 0; reg < 4; reg++) {
            int row = q * 4 + reg;
            hsN[row][col ^ ((row & 7) << 3)] = f2bf(fmaxf(acc[reg], 0.f));
        }
    }
    __syncthreads();

    if (FINAL == 0) {
        // ---- mm1 on h_next ----
        f32x4 aacc, bacc;
        {
            float bv = msg_b[ct * 16 + cl];
            aacc = (f32x4){bv, bv, bv, bv};
            bacc = (f32x4){0.f, 0.f, 0.f, 0.f};
        }
#pragma unroll
        for (int ks = 0; ks < 4; ks++) {
            bf16x8 hF2 = ldfragA(hsN, cl, ks, q);
            bf16x8 w1 = *(const bf16x8*)&wd[((ct * 4 + ks) * 64 + lane) * 8];
            bf16x8 w2 = *(const bf16x8*)&wsr[((ct * 4 + ks) * 64 + lane) * 8];
            aacc = __builtin_amdgcn_mfma_f32_16x16x32_bf16(hF2, w1, aacc, 0, 0, 0);
            bacc = __builtin_amdgcn_mfma_f32_16x16x32_bf16(hF2, w2, bacc, 0, 0, 0);
        }
        {
            int col = ct * 16 + cl;
#pragma unroll
            for (int reg = 0; reg < 4; reg++) {
                int row = n0 + q * 4 + reg;
                Aout[(size_t)row * HD + col] = f2bf(aacc[reg]);
                Bout[(size_t)row * HD + col] = f2bf(bacc[reg]);
            }
        }
        // h writeback
        __syncthreads();
        if (t < LROWS * 16) {
            int row = t >> 4, ch = t & 15;
            *(bf16x8*)&h_bf[(size_t)(n0 + row) * HD + ch * 8] =
                *(const bf16x8*)&hsN[row][(ch ^ (row & 7)) * 8];
        }
    } else {
        // ---- decoder + termination partial: wave wv reduces rows wv*2..+1 ----
        float dw0 = dec_w[lane], dw1 = dec_w[64 + lane];
        float tw0 = term_w[lane], tw1 = term_w[64 + lane];
        float tsum = 0.f;
#pragma unroll
        for (int rr = 0; rr < 2; rr++) {
            int r = wv * 2 + rr;
            int sw = (r & 7) << 3;
            float h0 = bf2f(hsN[r][lane ^ sw]);
            float h1 = bf2f(hsN[r][(64 + lane) ^ sw]);
            float s1 = fmaf(h0, dw0, h1 * dw1);
            float s2 = fmaf(h0, tw0, h1 * tw1);
#pragma unroll
            for (int off = 32; off; off >>= 1) {
                s1 += __shfl_xor(s1, off);
                s2 += __shfl_xor(s2, off);
            }
            if (lane == 0) out[n0 + r] = 1.f / (1.f + expf(-(s1 + dec_b[0])));
            tsum += s2;
        }
        if (lane == 0) tred[wv] = tsum;
        __syncthreads();
        if (t == 0) {
            float s = 0.f;
#pragma unroll
            for (int i = 0; i < 8; i++) s += tred[i];
            partials[blockIdx.x] = s;
        }
    }
}

__global__ __launch_bounds__(256) void k_term(const float* __restrict__ partials,
                                              const float* __restrict__ term_b,
                                              float* __restrict__ out) {
    __shared__ float red[256];
    int t = threadIdx.x;
    float s = 0.f;
    for (int i = t; i < LNBLK; i += 256) s += partials[i];
    red[t] = s;
    __syncthreads();
    for (int off = 128; off; off >>= 1) {
        if (t < off) red[t] += red[t + off];
        __syncthreads();
    }
    if (t == 0) {
        float m = red[0] / (float)NN;
        out[NN] = 1.f / (1.f + expf(-(m + term_b[0])));
    }
}

extern "C" void kernel_launch(void* const* d_in, const int* in_sizes, int n_in,
                              void* d_out, int out_size, void* d_ws, size_t ws_size,
                              hipStream_t stream) {
    const float* x        = (const float*)d_in[0];
    const int*   eidx     = (const int*)d_in[1];
    const float* eattr    = (const float*)d_in[2];
    const float* enc_w    = (const float*)d_in[3];
    const float* enc_b    = (const float*)d_in[4];
    const float* msg_w    = (const float*)d_in[5];
    const float* msg_b    = (const float*)d_in[6];
    const float* upd_w    = (const float*)d_in[7];
    const float* upd_b    = (const float*)d_in[8];
    const float* dec_w    = (const float*)d_in[9];
    const float* dec_b    = (const float*)d_in[10];
    const float* term_w   = (const float*)d_in[11];
    const float* term_b   = (const float*)d_in[12];
    float* out = (float*)d_out;

    const int* src = eidx;          // edge_index[0] = source j
    const int* dst = eidx + NE;     // edge_index[1] = target i

    char* ws = (char*)d_ws;
    size_t off = 0;
    auto alloc = [&](size_t bytes) -> void* {
        void* p = ws + off;
        off += (bytes + 255) & ~size_t(255);
        return p;
    };
    unsigned short* h_bf  = (unsigned short*)alloc((size_t)NN * HD * 2);
    unsigned short* A0    = (unsigned short*)alloc((size_t)NN * HD * 2);
    unsigned short* B0    = (unsigned short*)alloc((size_t)NN * HD * 2);
    unsigned short* A1    = (unsigned short*)alloc((size_t)NN * HD * 2);
    unsigned short* B1    = (unsigned short*)alloc((size_t)NN * HD * 2);
    unsigned* edges       = (unsigned*)alloc((size_t)NN * CAP * 4);
    unsigned short* wpack = (unsigned short*)alloc((size_t)4 * 16384 * 2);
    int*   cnt            = (int*)alloc((size_t)NN * 4);
    float* partials       = (float*)alloc((size_t)LNBLK * 4);

    // weight repack + cnt zeroing (one dispatch)
    k_pack_fill<<<(8192 + NN + 255) / 256, 256, 0, stream>>>(msg_w, upd_w, wpack, cnt);
    // XCD-partitioned bucket scatter
    k_scatter<<<NPART * 128, 256, 0, stream>>>(src, (const int4*)dst, eattr, cnt, edges);
    // encoder + first message linear + bucket padding
    k_enc_mm1<<<NBLK, 128, 0, stream>>>(x, enc_w, enc_b, wpack, msg_b, h_bf, A0, B0,
                                        cnt, edges);

    // fused layers (A/B double-buffered)
    k_layer<0><<<LNBLK, 512, 0, stream>>>(h_bf, A0, B0, cnt, edges, msg_w, wpack,
                                          upd_b, msg_b, A1, B1,
                                          dec_w, dec_b, term_w, out, partials);
    k_layer<0><<<LNBLK, 512, 0, stream>>>(h_bf, A1, B1, cnt, edges, msg_w, wpack,
                                          upd_b, msg_b, A0, B0,
                                          dec_w, dec_b, term_w, out, partials);
    k_layer<1><<<LNBLK, 512, 0, stream>>>(h_bf, A0, B0, cnt, edges, msg_w, wpack,
                                          upd_b, msg_b, A1, B1,
                                          dec_w, dec_b, term_w, out, partials);

    k_term<<<1, 256, 0, stream>>>(partials, term_b, out);
}

// Round 19
// 135.640 us; speedup vs baseline: 1.0795x; 1.0771x over previous
//
#include <hip/hip_runtime.h>
#include <math.h>

#define NN 20000
#define NE 640000
#define HD 128
#define ROWS 32                // encoder tile
#define NBLK (NN / ROWS)       // 625 (encoder grid)
#define LROWS 16               // layer tile
#define LNBLK (NN / LROWS)     // 1250 (layer grid)
#define CAP 96                 // max degree capacity (Poisson(32) max ~60)
#define NPART 8
#define PART_SZ (NN / NPART)   // 2500

typedef __attribute__((ext_vector_type(8))) short bf16x8;
typedef __attribute__((ext_vector_type(4))) float f32x4;

__device__ __forceinline__ unsigned short f2bf(float f) {
    unsigned u = __float_as_uint(f);
    unsigned r = u + 0x7FFFu + ((u >> 16) & 1u);   // RNE
    return (unsigned short)(r >> 16);
}
__device__ __forceinline__ float bf2f(unsigned short b) {
    return __uint_as_float(((unsigned)b) << 16);
}

// edge record: src (15 bits) << 17 | ea as 17-bit fixed point [0,1)
__device__ __forceinline__ unsigned pack_edge(int src, float ea) {
    return ((unsigned)src << 17) | (unsigned)(ea * 131072.0f);
}

// ---------------- weight repack + cnt zero (fused) ----------------
__global__ __launch_bounds__(256) void k_pack_fill(const float* __restrict__ msg_w,
                                                   const float* __restrict__ upd_w,
                                                   unsigned short* __restrict__ wp,
                                                   int* __restrict__ cnt) {
    int tid = blockIdx.x * 256 + threadIdx.x;
    if (tid < 8192) {
        int m = tid >> 11;
        int rem = tid & 2047;
        int ct = rem >> 8;
        int ks = (rem >> 6) & 3;
        int lane = rem & 63;
        const float* W = (m == 0) ? msg_w
                       : (m == 1) ? msg_w + HD * HD
                       : (m == 2) ? upd_w
                                  : upd_w + HD * HD;
        int k0 = ks * 32 + (lane >> 4) * 8;
        int col = ct * 16 + (lane & 15);
        unsigned short* outp = wp + (size_t)m * 16384 + ((ct * 4 + ks) * 64 + lane) * 8;
#pragma unroll
        for (int j = 0; j < 8; j++) outp[j] = f2bf(W[(k0 + j) * HD + col]);
    }
    int z = tid - 8192;
    if (z >= 0 && z < NN) cnt[z] = 0;
}

// ---------------- XCD-partitioned bucket scatter ----------------
__global__ __launch_bounds__(256) void k_scatter(const int* __restrict__ src,
                                                 const int4* __restrict__ dst4,
                                                 const float* __restrict__ ea,
                                                 int* __restrict__ cnt,
                                                 unsigned* __restrict__ edges) {
    int part = blockIdx.x & (NPART - 1);
    int blk = blockIdx.x >> 3;
    int nblk = gridDim.x >> 3;
    int lo = part * PART_SZ;
    for (int e4 = blk * 256 + threadIdx.x; e4 < NE / 4; e4 += nblk * 256) {
        int4 d = dst4[e4];
        int e = e4 * 4;
        if ((unsigned)(d.x - lo) < (unsigned)PART_SZ) {
            int p = atomicAdd(&cnt[d.x], 1);
            if (p < CAP) edges[(size_t)d.x * CAP + p] = pack_edge(src[e], ea[e]);
        }
        if ((unsigned)(d.y - lo) < (unsigned)PART_SZ) {
            int p = atomicAdd(&cnt[d.y], 1);
            if (p < CAP) edges[(size_t)d.y * CAP + p] = pack_edge(src[e + 1], ea[e + 1]);
        }
        if ((unsigned)(d.z - lo) < (unsigned)PART_SZ) {
            int p = atomicAdd(&cnt[d.z], 1);
            if (p < CAP) edges[(size_t)d.z * CAP + p] = pack_edge(src[e + 2], ea[e + 2]);
        }
        if ((unsigned)(d.w - lo) < (unsigned)PART_SZ) {
            int p = atomicAdd(&cnt[d.w], 1);
            if (p < CAP) edges[(size_t)d.w * CAP + p] = pack_edge(src[e + 3], ea[e + 3]);
        }
    }
}

// ---------------- MFMA helpers ----------------
__device__ __forceinline__ bf16x8 ldfragA(const unsigned short S[][HD], int row, int ks, int q) {
    int k0 = (ks * 32 + q * 8) ^ ((row & 7) << 3);
    return *(const bf16x8*)&S[row][k0];
}

// ---------------- encoder + mm1 (MFMA, 128 threads, 32 rows) + bucket padding ----------------
__global__ __launch_bounds__(128) void k_enc_mm1(const float* __restrict__ x,
                                                 const float* __restrict__ enc_w,
                                                 const float* __restrict__ enc_b,
                                                 const unsigned short* __restrict__ wp,
                                                 const float* __restrict__ msg_b,
                                                 unsigned short* __restrict__ h_bf,
                                                 unsigned short* __restrict__ Abf,
                                                 unsigned short* __restrict__ Bbf,
                                                 const int* __restrict__ cnt,
                                                 unsigned* __restrict__ edges) {
    __shared__ unsigned short hsN[ROWS][HD];
    int t = threadIdx.x;
    int n0 = blockIdx.x * ROWS;
    // pad each node's bucket to a multiple of 16 by replicating edge 0
    // (max is idempotent under duplicates; removes the gather tail in k_layer)
    if (t < ROWS) {
        int i = n0 + t;
        int ci = cnt[i];
        if (ci > CAP) ci = CAP;
        if (ci > 0) {
            int ce = (ci + 15) & ~15;
            if (ce > CAP) ce = CAP;
            unsigned e0 = edges[(size_t)i * CAP];
            for (int j = ci; j < ce; j++) edges[(size_t)i * CAP + j] = e0;
        }
    }
    {
        float ew = enc_w[t], eb = enc_b[t];
#pragma unroll
        for (int r = 0; r < ROWS; r++) {
            unsigned short bv = f2bf(fmaf(x[n0 + r], ew, eb));
            hsN[r][t ^ ((r & 7) << 3)] = bv;
            h_bf[(size_t)(n0 + r) * HD + t] = bv;
        }
    }
    __syncthreads();
    int lane = t & 63, wv = t >> 6;
    int rbase = wv * 16;
    int cl = lane & 15, q = lane >> 4;
    const unsigned short* wd = wp;
    const unsigned short* wsr = wp + 16384;
    f32x4 aacc[8], bacc[8];
#pragma unroll
    for (int ct = 0; ct < 8; ct++) {
        float bv = msg_b[ct * 16 + cl];
        aacc[ct] = (f32x4){bv, bv, bv, bv};
        bacc[ct] = (f32x4){0.f, 0.f, 0.f, 0.f};
    }
#pragma unroll
    for (int ks = 0; ks < 4; ks++) {
        bf16x8 hF = ldfragA(hsN, rbase + cl, ks, q);
#pragma unroll
        for (int ct = 0; ct < 8; ct++) {
            bf16x8 w1 = *(const bf16x8*)&wd[((ct * 4 + ks) * 64 + lane) * 8];
            bf16x8 w2 = *(const bf16x8*)&wsr[((ct * 4 + ks) * 64 + lane) * 8];
            aacc[ct] = __builtin_amdgcn_mfma_f32_16x16x32_bf16(hF, w1, aacc[ct], 0, 0, 0);
            bacc[ct] = __builtin_amdgcn_mfma_f32_16x16x32_bf16(hF, w2, bacc[ct], 0, 0, 0);
        }
    }
#pragma unroll
    for (int ct = 0; ct < 8; ct++) {
        int col = ct * 16 + cl;
#pragma unroll
        for (int reg = 0; reg < 4; reg++) {
            int row = n0 + rbase + q * 4 + reg;
            Abf[(size_t)row * HD + col] = f2bf(aacc[ct][reg]);
            Bbf[(size_t)row * HD + col] = f2bf(bacc[ct][reg]);
        }
    }
}

// ---------------- fused layer: aggr + mm2 + [mm1 | decoder] ----------------
// 512 threads = 8 waves, 16 nodes/block. Edge records staged to LDS
// (contiguous 6 KB, fully coalesced); gather batched 16-wide, no tail.
template <int FINAL>
__global__ __launch_bounds__(512) void k_layer(unsigned short* __restrict__ h_bf,
                                               const unsigned short* __restrict__ Ain,
                                               const unsigned short* __restrict__ Bin,
                                               const int* __restrict__ cnt,
                                               const unsigned* __restrict__ edges,
                                               const float* __restrict__ msg_w,
                                               const unsigned short* __restrict__ wp,
                                               const float* __restrict__ upd_b,
                                               const float* __restrict__ msg_b,
                                               unsigned short* __restrict__ Aout,
                                               unsigned short* __restrict__ Bout,
                                               const float* __restrict__ dec_w,
                                               const float* __restrict__ dec_b,
                                               const float* __restrict__ term_w,
                                               float* __restrict__ out,
                                               float* __restrict__ partials) {
    __shared__ unsigned short hsA[LROWS][HD];
    __shared__ unsigned short hsG[LROWS][HD];
    __shared__ unsigned short hsN[LROWS][HD];
    __shared__ unsigned erec[LROWS * CAP];   // 6 KB, block's 16 buckets
    __shared__ float tred[8];
    int t = threadIdx.x;
    int wv = t >> 6, lane = t & 63;
    int n0 = blockIdx.x * LROWS;

    // prefetch h rows into registers (t<256 covers 16 rows x 16 chunks)
    bf16x8 hpre;
    if (t < LROWS * 16) {
        int row = t >> 4, ch = t & 15;
        hpre = *(const bf16x8*)&h_bf[(size_t)(n0 + row) * HD + ch * 8];
    }

    // stage the block's edge records into LDS: contiguous region, coalesced
    {
        const unsigned* eg = edges + (size_t)n0 * CAP;
#pragma unroll
        for (int v = 0; v < (LROWS * CAP) / 512; v++)   // 1536/512 = 3
            erec[t + v * 512] = eg[t + v * 512];
    }

    // hoisted per-node metadata (overlaps the staging)
    int i0 = n0 + wv * 2;
    int ci0 = cnt[i0], ci1 = cnt[i0 + 1];
    if (ci0 > CAP) ci0 = CAP;
    if (ci1 > CAP) ci1 = CAP;
    unsigned av0 = ((const unsigned*)Ain)[(size_t)i0 * 64 + lane];
    unsigned av1 = ((const unsigned*)Ain)[(size_t)(i0 + 1) * 64 + lane];
    __syncthreads();   // erec ready

    // ---- phase A: aggregation, 2 nodes per wave, batch-16 gather (records in LDS) ----
    float2 w = ((const float2*)(msg_w + 256 * HD))[lane];
    const float SC = 1.0f / 131072.0f;
    const unsigned* B32 = (const unsigned*)Bin;
#pragma unroll
    for (int k = 0; k < 2; k++) {
        int ri = wv * 2 + k;
        int ci = k ? ci1 : ci0;
        unsigned av = k ? av1 : av0;
        const unsigned* ep = &erec[ri * CAP];
        float m0 = -INFINITY, m1 = -INFINITY;
        int nb = (ci + 15) >> 4;       // padded: no scalar tail
        for (int bi = 0; bi < nb; bi++) {
            unsigned p[16], b[16];
#pragma unroll
            for (int u = 0; u < 16; u++) p[u] = ep[bi * 16 + u];   // LDS reads
#pragma unroll
            for (int u = 0; u < 16; u++)
                b[u] = B32[(size_t)(p[u] >> 17) * 64 + lane];      // 16 loads in flight
#pragma unroll
            for (int u = 0; u < 16; u++) {
                float ea = (float)(p[u] & 0x1FFFF) * SC;
                m0 = fmaxf(m0, fmaf(ea, w.x, bf2f((unsigned short)b[u])));
                m1 = fmaxf(m1, fmaf(ea, w.y, bf2f((unsigned short)(b[u] >> 16))));
            }
        }
        unsigned short r0 = f2bf(fmaxf(bf2f((unsigned short)av) + m0, 0.f));
        unsigned short r1 = f2bf(fmaxf(bf2f((unsigned short)(av >> 16)) + m1, 0.f));
        int e0 = (2 * lane) ^ ((ri & 7) << 3);
        *(unsigned*)&hsG[ri][e0] = ((unsigned)r1 << 16) | r0;
    }
    // stash prefetched h into swizzled LDS
    if (t < LROWS * 16) {
        int row = t >> 4, ch = t & 15;
        *(bf16x8*)&hsA[row][(ch ^ (row & 7)) * 8] = hpre;
    }
    __syncthreads();

    // ---- phase B: mm2 — 8 waves, wave wv owns col-tile wv ----
    int q = lane >> 4, cl = lane & 15;
    int ct = wv;
    const unsigned short* wd = wp;
    const unsigned short* wsr = wp + 16384;
    const unsigned short* wu1 = wp + 2 * 16384;
    const unsigned short* wu2 = wp + 3 * 16384;
    f32x4 acc;
    {
        float bv = upd_b[ct * 16 + cl];
        acc = (f32x4){bv, bv, bv, bv};
    }
#pragma unroll
    for (int ks = 0; ks < 4; ks++) {
        bf16x8 hF = ldfragA(hsA, cl, ks, q);
        bf16x8 gF = ldfragA(hsG, cl, ks, q);
        bf16x8 w1 = *(const bf16x8*)&wu1[((ct * 4 + ks) * 64 + lane) * 8];
        bf16x8 w2 = *(const bf16x8*)&wu2[((ct * 4 + ks) * 64 + lane) * 8];
        acc = __builtin_amdgcn_mfma_f32_16x16x32_bf16(hF, w1, acc, 0, 0, 0);
        acc = __builtin_amdgcn_mfma_f32_16x16x32_bf16(gF, w2, acc, 0, 0, 0);
    }
    {
        int col = ct * 16 + cl;
#pragma unroll
        for (int reg = 0; reg < 4; reg++) {
            int row = q * 4 + reg;
            hsN[row][col ^ ((row & 7) << 3)] = f2bf(fmaxf(acc[reg], 0.f));
        }
    }
    __syncthreads();

    if (FINAL == 0) {
        // ---- mm1 on h_next ----
        f32x4 aacc, bacc;
        {
            float bv = msg_b[ct * 16 + cl];
            aacc = (f32x4){bv, bv, bv, bv};
            bacc = (f32x4){0.f, 0.f, 0.f, 0.f};
        }
#pragma unroll
        for (int ks = 0; ks < 4; ks++) {
            bf16x8 hF2 = ldfragA(hsN, cl, ks, q);
            bf16x8 w1 = *(const bf16x8*)&wd[((ct * 4 + ks) * 64 + lane) * 8];
            bf16x8 w2 = *(const bf16x8*)&wsr[((ct * 4 + ks) * 64 + lane) * 8];
            aacc = __builtin_amdgcn_mfma_f32_16x16x32_bf16(hF2, w1, aacc, 0, 0, 0);
            bacc = __builtin_amdgcn_mfma_f32_16x16x32_bf16(hF2, w2, bacc, 0, 0, 0);
        }
        {
            int col = ct * 16 + cl;
#pragma unroll
            for (int reg = 0; reg < 4; reg++) {
                int row = n0 + q * 4 + reg;
                Aout[(size_t)row * HD + col] = f2bf(aacc[reg]);
                Bout[(size_t)row * HD + col] = f2bf(bacc[reg]);
            }
        }
        // h writeback
        __syncthreads();
        if (t < LROWS * 16) {
            int row = t >> 4, ch = t & 15;
            *(bf16x8*)&h_bf[(size_t)(n0 + row) * HD + ch * 8] =
                *(const bf16x8*)&hsN[row][(ch ^ (row & 7)) * 8];
        }
    } else {
        // ---- decoder + termination partial: wave wv reduces rows wv*2..+1 ----
        float dw0 = dec_w[lane], dw1 = dec_w[64 + lane];
        float tw0 = term_w[lane], tw1 = term_w[64 + lane];
        float tsum = 0.f;
#pragma unroll
        for (int rr = 0; rr < 2; rr++) {
            int r = wv * 2 + rr;
            int sw = (r & 7) << 3;
            float h0 = bf2f(hsN[r][lane ^ sw]);
            float h1 = bf2f(hsN[r][(64 + lane) ^ sw]);
            float s1 = fmaf(h0, dw0, h1 * dw1);
            float s2 = fmaf(h0, tw0, h1 * tw1);
#pragma unroll
            for (int off = 32; off; off >>= 1) {
                s1 += __shfl_xor(s1, off);
                s2 += __shfl_xor(s2, off);
            }
            if (lane == 0) out[n0 + r] = 1.f / (1.f + expf(-(s1 + dec_b[0])));
            tsum += s2;
        }
        if (lane == 0) tred[wv] = tsum;
        __syncthreads();
        if (t == 0) {
            float s = 0.f;
#pragma unroll
            for (int i = 0; i < 8; i++) s += tred[i];
            partials[blockIdx.x] = s;
        }
    }
}

__global__ __launch_bounds__(256) void k_term(const float* __restrict__ partials,
                                              const float* __restrict__ term_b,
                                              float* __restrict__ out) {
    __shared__ float red[256];
    int t = threadIdx.x;
    float s = 0.f;
    for (int i = t; i < LNBLK; i += 256) s += partials[i];
    red[t] = s;
    __syncthreads();
    for (int off = 128; off; off >>= 1) {
        if (t < off) red[t] += red[t + off];
        __syncthreads();
    }
    if (t == 0) {
        float m = red[0] / (float)NN;
        out[NN] = 1.f / (1.f + expf(-(m + term_b[0])));
    }
}

extern "C" void kernel_launch(void* const* d_in, const int* in_sizes, int n_in,
                              void* d_out, int out_size, void* d_ws, size_t ws_size,
                              hipStream_t stream) {
    const float* x        = (const float*)d_in[0];
    const int*   eidx     = (const int*)d_in[1];
    const float* eattr    = (const float*)d_in[2];
    const float* enc_w    = (const float*)d_in[3];
    const float* enc_b    = (const float*)d_in[4];
    const float* msg_w    = (const float*)d_in[5];
    const float* msg_b    = (const float*)d_in[6];
    const float* upd_w    = (const float*)d_in[7];
    const float* upd_b    = (const float*)d_in[8];
    const float* dec_w    = (const float*)d_in[9];
    const float* dec_b    = (const float*)d_in[10];
    const float* term_w   = (const float*)d_in[11];
    const float* term_b   = (const float*)d_in[12];
    float* out = (float*)d_out;

    const int* src = eidx;          // edge_index[0] = source j
    const int* dst = eidx + NE;     // edge_index[1] = target i

    char* ws = (char*)d_ws;
    size_t off = 0;
    auto alloc = [&](size_t bytes) -> void* {
        void* p = ws + off;
        off += (bytes + 255) & ~size_t(255);
        return p;
    };
    unsigned short* h_bf  = (unsigned short*)alloc((size_t)NN * HD * 2);
    unsigned short* A0    = (unsigned short*)alloc((size_t)NN * HD * 2);
    unsigned short* B0    = (unsigned short*)alloc((size_t)NN * HD * 2);
    unsigned short* A1    = (unsigned short*)alloc((size_t)NN * HD * 2);
    unsigned short* B1    = (unsigned short*)alloc((size_t)NN * HD * 2);
    unsigned* edges       = (unsigned*)alloc((size_t)NN * CAP * 4);
    unsigned short* wpack = (unsigned short*)alloc((size_t)4 * 16384 * 2);
    int*   cnt            = (int*)alloc((size_t)NN * 4);
    float* partials       = (float*)alloc((size_t)LNBLK * 4);

    // weight repack + cnt zeroing (one dispatch)
    k_pack_fill<<<(8192 + NN + 255) / 256, 256, 0, stream>>>(msg_w, upd_w, wpack, cnt);
    // XCD-partitioned bucket scatter
    k_scatter<<<NPART * 128, 256, 0, stream>>>(src, (const int4*)dst, eattr, cnt, edges);
    // encoder + first message linear + bucket padding
    k_enc_mm1<<<NBLK, 128, 0, stream>>>(x, enc_w, enc_b, wpack, msg_b, h_bf, A0, B0,
                                        cnt, edges);

    // fused layers (A/B double-buffered)
    k_layer<0><<<LNBLK, 512, 0, stream>>>(h_bf, A0, B0, cnt, edges, msg_w, wpack,
                                          upd_b, msg_b, A1, B1,
                                          dec_w, dec_b, term_w, out, partials);
    k_layer<0><<<LNBLK, 512, 0, stream>>>(h_bf, A1, B1, cnt, edges, msg_w, wpack,
                                          upd_b, msg_b, A0, B0,
                                          dec_w, dec_b, term_w, out, partials);
    k_layer<1><<<LNBLK, 512, 0, stream>>>(h_bf, A0, B0, cnt, edges, msg_w, wpack,
                                          upd_b, msg_b, A1, B1,
                                          dec_w, dec_b, term_w, out, partials);

    k_term<<<1, 256, 0, stream>>>(partials, term_b, out);
}